// Round 1
// baseline (887.595 us; speedup 1.0000x reference)
//
#include <hip/hip_runtime.h>

// Problem: B=64, L=512, H2=1536, T=64.
// logits = x@W + b  -> softmax -> loss vs closed-form y; argmax accuracy.
// Rows = B*L = 32768. Lane = output column (T=64 == wave width).
// Each wave: 16 rows, all 64 cols. W chunk in VGPRs, x via wave-uniform
// scalar loads (v_fmac_f32 with SGPR operand).

#define H2 1536
#define NT 64
#define ROWS (64 * 512)
#define KC 32          // K-chunk held in VGPRs per wave
#define RPW 16         // rows per wave
#define WPB 4          // waves per block

__global__ __launch_bounds__(256, 2) void mlaner_main(
    const float* __restrict__ x, const float* __restrict__ W,
    const float* __restrict__ bias, const int* __restrict__ tags,
    const float* __restrict__ tag_to_score, const int* __restrict__ tptr,
    float* __restrict__ ws_loss, unsigned int* __restrict__ ws_cnt)
{
    const int lane = threadIdx.x & 63;
    const int wave = __builtin_amdgcn_readfirstlane(threadIdx.x >> 6);
    const int row0 = (blockIdx.x * WPB + wave) * RPW;

    float acc[RPW];
#pragma unroll
    for (int r = 0; r < RPW; ++r) acc[r] = 0.0f;

    const float* __restrict__ wcol = W + lane;   // W[k*NT + lane]
    for (int k0 = 0; k0 < H2; k0 += KC) {
        float wreg[KC];
#pragma unroll
        for (int kc = 0; kc < KC; ++kc)
            wreg[kc] = wcol[(size_t)(k0 + kc) * NT];
#pragma unroll
        for (int r = 0; r < RPW; ++r) {
            const float* __restrict__ xr = x + (size_t)(row0 + r) * H2 + k0;
#pragma unroll
            for (int kc = 0; kc < KC; ++kc)
                acc[r] = fmaf(xr[kc], wreg[kc], acc[r]);  // xr[kc] is wave-uniform -> SGPR
        }
    }

    // ---- epilogue: per-row softmax + loss + argmax ----
    // attention_mask adds a per-row constant across the tag dim -> softmax,
    // log-softmax, and argmax are invariant to it; skipped by construction.
    const float bv = bias[lane];
    const int tt = tptr[0];
    const float e1 = expf(1.0f);
    float loss_acc = 0.0f;
    unsigned right_acc = 0, valid_acc = 0;

#pragma unroll 1
    for (int r = 0; r < RPW; ++r) {
        const int row = row0 + r;
        float l = acc[r] + bv;

        float m = l;
#pragma unroll
        for (int off = 32; off >= 1; off >>= 1)
            m = fmaxf(m, __shfl_xor(m, off, 64));

        float e = expf(l - m);
        float Z = e;
#pragma unroll
        for (int off = 32; off >= 1; off >>= 1)
            Z += __shfl_xor(Z, off, 64);

        float lp = logf(e / Z + 1e-10f);   // log(p + 1e-10), matching reference
        float slp = lp;
#pragma unroll
        for (int off = 32; off >= 1; off >>= 1)
            slp += __shfl_xor(slp, off, 64);

        // argmax with numpy first-index tie semantics
        unsigned long long bal = __ballot(l == m);
        int pred = __ffsll((long long)bal) - 1;

        const int tag = tags[row];
        float lptag = __shfl(lp, tag, 64);

        // y = softmax over {1,...,1, s at tag}, s = tag_to_score[tag]^t
        float sc = tag_to_score[tag];
        float s = powf(sc, (float)tt);
        float es = expf(s);
        float denom = 63.0f * e1 + es;
        float y_other = e1 / denom;
        float y_tag = es / denom;
        loss_acc -= y_other * (slp - lptag) + y_tag * lptag;

        const unsigned valid = (tag < NT - 3) ? 1u : 0u;
        valid_acc += valid;
        right_acc += (valid && (pred == tag)) ? 1u : 0u;
    }

    if (lane == 0) {
        atomicAdd(ws_loss, loss_acc);
        atomicAdd(ws_cnt + 0, right_acc);
        atomicAdd(ws_cnt + 1, valid_acc);
    }
}

__global__ void mlaner_final(const float* __restrict__ ws_loss,
                             const unsigned int* __restrict__ ws_cnt,
                             float* __restrict__ out)
{
    out[0] = ws_loss[0];
    out[1] = (float)ws_cnt[0] / (float)ws_cnt[1];
}

extern "C" void kernel_launch(void* const* d_in, const int* in_sizes, int n_in,
                              void* d_out, int out_size, void* d_ws, size_t ws_size,
                              hipStream_t stream)
{
    const float* x    = (const float*)d_in[0];   // [64,512,1536] fp32
    const float* W    = (const float*)d_in[1];   // [1536,64] fp32
    const float* b    = (const float*)d_in[2];   // [64] fp32
    const int*   tags = (const int*)d_in[3];     // [64,512] int
    // d_in[4]: attention_mask [64,512] fp32 — softmax-shift-invariant, unused.
    const float* t2s  = (const float*)d_in[5];   // [64] fp32
    const int*   tptr = (const int*)d_in[6];     // scalar t
    float* out = (float*)d_out;                  // [loss1, acc1]

    float* ws_loss = (float*)d_ws;
    unsigned int* ws_cnt = (unsigned int*)((char*)d_ws + 8);

    hipMemsetAsync(d_ws, 0, 16, stream);
    mlaner_main<<<dim3(ROWS / (RPW * WPB)), dim3(256), 0, stream>>>(
        x, W, b, tags, t2s, tptr, ws_loss, ws_cnt);
    mlaner_final<<<dim3(1), dim3(1), 0, stream>>>(ws_loss, ws_cnt, out);
}

// Round 2
// 667.808 us; speedup vs baseline: 1.3291x; 1.3291x over previous
//
#include <hip/hip_runtime.h>

// Problem: B=64, L=512, H2=1536, T=64.
// logits = x@W + b -> softmax -> loss vs closed-form y; argmax accuracy.
// Rows = B*L = 32768. Lane = output column (T=64 == wave width).
//
// R2 design: small register tile the compiler will keep resident.
//   KC=8 k-slice in wreg[8] (VGPR, lane-varying W column values),
//   RPW=8 rows, x values wave-uniform -> scalar loads (SGPR, lgkmcnt)
//   while W loads track vmcnt -> independent counters, pipelineable.
//   No barriers: 4 blocks/CU * 4 waves free-run to hide L1/L2 latency.

#define H2 1536
#define NT 64
#define ROWS (64 * 512)
#define KC 8           // K-chunk held in VGPRs per wave
#define RPW 8          // rows per wave
#define WPB 4          // waves per block

__global__ __launch_bounds__(256, 4) void mlaner_main(
    const float* __restrict__ x, const float* __restrict__ W,
    const float* __restrict__ bias, const int* __restrict__ tags,
    const float* __restrict__ tag_to_score, const int* __restrict__ tptr,
    float* __restrict__ ws_loss, unsigned int* __restrict__ ws_cnt)
{
    const int lane = threadIdx.x & 63;
    const int wave = __builtin_amdgcn_readfirstlane(threadIdx.x >> 6);
    const int row0 = (blockIdx.x * WPB + wave) * RPW;

    float acc[RPW];
#pragma unroll
    for (int r = 0; r < RPW; ++r) acc[r] = 0.0f;

    const float* __restrict__ wcol = W + lane;            // W[k*NT + lane]
    const float* __restrict__ xbase = x + (size_t)row0 * H2;

#pragma unroll 1
    for (int k0 = 0; k0 < H2; k0 += KC) {
        // x chunk: wave-uniform addresses -> scalar loads (SGPRs)
        float xs[RPW][KC];
#pragma unroll
        for (int r = 0; r < RPW; ++r) {
            const float* __restrict__ xr = xbase + r * H2 + k0;
#pragma unroll
            for (int j = 0; j < KC; ++j) xs[r][j] = xr[j];
        }
        // W chunk: one value per lane per k (vector loads, L1/L2-hot)
        float wreg[KC];
#pragma unroll
        for (int j = 0; j < KC; ++j)
            wreg[j] = wcol[(size_t)(k0 + j) * NT];
        // 64 fmacs, all operands in registers
#pragma unroll
        for (int j = 0; j < KC; ++j) {
#pragma unroll
            for (int r = 0; r < RPW; ++r)
                acc[r] = fmaf(xs[r][j], wreg[j], acc[r]);
        }
    }

    // ---- epilogue: per-row softmax + loss + argmax ----
    // attention_mask adds a per-row constant across the tag dim -> softmax,
    // log-softmax, and argmax are invariant to it; skipped by construction.
    const float bv = bias[lane];
    const int tt = tptr[0];
    const float e1 = expf(1.0f);
    float loss_acc = 0.0f;
    unsigned right_acc = 0, valid_acc = 0;

#pragma unroll 1
    for (int r = 0; r < RPW; ++r) {
        const int row = row0 + r;
        float l = acc[r] + bv;

        float m = l;
#pragma unroll
        for (int off = 32; off >= 1; off >>= 1)
            m = fmaxf(m, __shfl_xor(m, off, 64));

        float e = expf(l - m);
        float Z = e;
#pragma unroll
        for (int off = 32; off >= 1; off >>= 1)
            Z += __shfl_xor(Z, off, 64);

        float lp = logf(e / Z + 1e-10f);   // log(p + 1e-10), matching reference
        float slp = lp;
#pragma unroll
        for (int off = 32; off >= 1; off >>= 1)
            slp += __shfl_xor(slp, off, 64);

        // argmax with numpy first-index tie semantics
        unsigned long long bal = __ballot(l == m);
        int pred = __ffsll((long long)bal) - 1;

        const int tag = tags[row];
        float lptag = __shfl(lp, tag, 64);

        // y = softmax over {1,...,1, s at tag}, s = tag_to_score[tag]^t
        float sc = tag_to_score[tag];
        float s = powf(sc, (float)tt);
        float es = expf(s);
        float denom = 63.0f * e1 + es;
        float y_other = e1 / denom;
        float y_tag = es / denom;
        loss_acc -= y_other * (slp - lptag) + y_tag * lptag;

        const unsigned valid = (tag < NT - 3) ? 1u : 0u;
        valid_acc += valid;
        right_acc += (valid && (pred == tag)) ? 1u : 0u;
    }

    if (lane == 0) {
        atomicAdd(ws_loss, loss_acc);
        atomicAdd(ws_cnt + 0, right_acc);
        atomicAdd(ws_cnt + 1, valid_acc);
    }
}

__global__ void mlaner_final(const float* __restrict__ ws_loss,
                             const unsigned int* __restrict__ ws_cnt,
                             float* __restrict__ out)
{
    out[0] = ws_loss[0];
    out[1] = (float)ws_cnt[0] / (float)ws_cnt[1];
}

extern "C" void kernel_launch(void* const* d_in, const int* in_sizes, int n_in,
                              void* d_out, int out_size, void* d_ws, size_t ws_size,
                              hipStream_t stream)
{
    const float* x    = (const float*)d_in[0];   // [64,512,1536] fp32
    const float* W    = (const float*)d_in[1];   // [1536,64] fp32
    const float* b    = (const float*)d_in[2];   // [64] fp32
    const int*   tags = (const int*)d_in[3];     // [64,512] int
    // d_in[4]: attention_mask [64,512] fp32 — softmax-shift-invariant, unused.
    const float* t2s  = (const float*)d_in[5];   // [64] fp32
    const int*   tptr = (const int*)d_in[6];     // scalar t
    float* out = (float*)d_out;                  // [loss1, acc1]

    float* ws_loss = (float*)d_ws;
    unsigned int* ws_cnt = (unsigned int*)((char*)d_ws + 8);

    hipMemsetAsync(d_ws, 0, 16, stream);
    mlaner_main<<<dim3(ROWS / (RPW * WPB)), dim3(256), 0, stream>>>(
        x, W, b, tags, t2s, tptr, ws_loss, ws_cnt);
    mlaner_final<<<dim3(1), dim3(1), 0, stream>>>(ws_loss, ws_cnt, out);
}

// Round 3
// 381.200 us; speedup vs baseline: 2.3284x; 1.7519x over previous
//
#include <hip/hip_runtime.h>
#include <hip/hip_bf16.h>

// B=64, L=512, H2=1536, T=64. logits = x@W + b -> softmax -> loss/acc.
// R3: bf16 MFMA (16x16x32) with 2-word split for fp32-grade precision:
//   x ~ xh + xl, W ~ wh + wl (bf16 RNE + bf16 residual)
//   x*W ~ xh*wh + xh*wl + xl*wh   (xl*wl ~ 2^-18 rel, dropped)
// Wave = 16 rows x 64 cols (4 B-tiles). W pre-packed into B-fragment order
// (hi/lo) in d_ws by a prep kernel; A converted in-register from fp32 x.
// HBM-bound target: x read once = 192 MB / 6.3 TB/s ~ 31 us.

#define H2 1536
#define NT 64
#define ROWS (64 * 512)
#define KSTEPS 48      // H2 / 32

typedef __attribute__((ext_vector_type(8))) short short8;
typedef __attribute__((ext_vector_type(4))) float f32x4;

// ws layout: [0..15] reduction slots; B-fragments at +256.
#define WS_B_OFF 256
#define B_FRAGS (KSTEPS * 4 * 64)           // 12288 fragments of 16B each

__device__ __forceinline__ short bf_hi(float f) {
    __hip_bfloat16 h = __float2bfloat16(f);          // RNE
    return __builtin_bit_cast(short, h);
}
__device__ __forceinline__ float bf_f(short s) {
    __hip_bfloat16 h = __builtin_bit_cast(__hip_bfloat16, s);
    return __bfloat162float(h);
}

// Pack W[k][n] (k-major, [1536][64]) into MFMA B-fragment order.
// Fragment (s, c, lane): k = s*32 + (lane>>4)*8 + j, n = c*16 + (lane&15).
__global__ void mlaner_prepw(const float* __restrict__ W,
                             short8* __restrict__ bhi, short8* __restrict__ blo)
{
    const int tid = blockIdx.x * 256 + threadIdx.x;   // 0..12287
    const int L = tid & 63, c = (tid >> 6) & 3, s = tid >> 8;
    const int kbase = s * 32 + (L >> 4) * 8;
    const int n = c * 16 + (L & 15);
    short8 hi, lo;
#pragma unroll
    for (int j = 0; j < 8; ++j) {
        float w = W[(size_t)(kbase + j) * NT + n];
        short h = bf_hi(w);
        hi[j] = h;
        lo[j] = bf_hi(w - bf_f(h));
    }
    const int idx = (s * 4 + c) * 64 + L;
    bhi[idx] = hi;
    blo[idx] = lo;
}

__device__ __forceinline__ void cvt_split(float4 a0, float4 a1,
                                          short8& hi, short8& lo)
{
    float v[8] = {a0.x, a0.y, a0.z, a0.w, a1.x, a1.y, a1.z, a1.w};
#pragma unroll
    for (int j = 0; j < 8; ++j) {
        short h = bf_hi(v[j]);
        hi[j] = h;
        lo[j] = bf_hi(v[j] - bf_f(h));
    }
}

__global__ __launch_bounds__(256, 2) void mlaner_main(
    const float* __restrict__ x,
    const short8* __restrict__ Bhi, const short8* __restrict__ Blo,
    const float* __restrict__ bias, const int* __restrict__ tags,
    const float* __restrict__ tag_to_score, const int* __restrict__ tptr,
    float* __restrict__ ws_loss, unsigned int* __restrict__ ws_cnt)
{
    const int lane = threadIdx.x & 63;
    const int wave = threadIdx.x >> 6;
    const int wid = blockIdx.x * 4 + wave;
    const int row0 = wid * 16;
    const int q = lane >> 4, n16 = lane & 15;

    // A-operand: lane holds x[row0 + n16][s*32 + q*8 + j], j=0..7
    const float* __restrict__ xp = x + (size_t)(row0 + n16) * H2 + q * 8;

    f32x4 acc[4];
#pragma unroll
    for (int c = 0; c < 4; ++c) acc[c] = (f32x4){0.f, 0.f, 0.f, 0.f};

    // prefetch: A two steps deep, B one step deep
    float4 a0_cur = *(const float4*)(xp + 0);
    float4 a1_cur = *(const float4*)(xp + 4);
    float4 a0_nxt = *(const float4*)(xp + 32);
    float4 a1_nxt = *(const float4*)(xp + 36);
    short8 bh[4], bl[4];
#pragma unroll
    for (int c = 0; c < 4; ++c) {
        bh[c] = Bhi[c * 64 + lane];
        bl[c] = Blo[c * 64 + lane];
    }

#pragma unroll 1
    for (int s = 0; s < KSTEPS; ++s) {
        const int sp2 = (s + 2 < KSTEPS) ? s + 2 : KSTEPS - 1;
        float4 a0_pf = *(const float4*)(xp + sp2 * 32);
        float4 a1_pf = *(const float4*)(xp + sp2 * 32 + 4);
        const int sp1 = (s + 1 < KSTEPS) ? s + 1 : KSTEPS - 1;
        short8 bhn[4], bln[4];
#pragma unroll
        for (int c = 0; c < 4; ++c) {
            bhn[c] = Bhi[(sp1 * 4 + c) * 64 + lane];
            bln[c] = Blo[(sp1 * 4 + c) * 64 + lane];
        }

        short8 ah, al;
        cvt_split(a0_cur, a1_cur, ah, al);
#pragma unroll
        for (int c = 0; c < 4; ++c) {
            acc[c] = __builtin_amdgcn_mfma_f32_16x16x32_bf16(ah, bh[c], acc[c], 0, 0, 0);
            acc[c] = __builtin_amdgcn_mfma_f32_16x16x32_bf16(ah, bl[c], acc[c], 0, 0, 0);
            acc[c] = __builtin_amdgcn_mfma_f32_16x16x32_bf16(al, bh[c], acc[c], 0, 0, 0);
        }

        a0_cur = a0_nxt; a1_cur = a1_nxt;
        a0_nxt = a0_pf;  a1_nxt = a1_pf;
#pragma unroll
        for (int c = 0; c < 4; ++c) { bh[c] = bhn[c]; bl[c] = bln[c]; }
    }

    // ---- epilogue ----
    // C/D layout: col = c*16 + n16, row(local) = q*4 + i  [m89-verified]
    // attention_mask adds a row constant -> softmax/argmax invariant; skipped.
    const float bv0 = bias[n16], bv1 = bias[16 + n16];
    const float bv2 = bias[32 + n16], bv3 = bias[48 + n16];
    int tg[4];
#pragma unroll
    for (int i = 0; i < 4; ++i) tg[i] = tags[row0 + q * 4 + i];
    const int tt = tptr[0];
    const float e1c = expf(1.0f);
    float loss_acc = 0.0f;
    unsigned right_acc = 0, valid_acc = 0;

#pragma unroll 1
    for (int i = 0; i < 4; ++i) {
        float l0 = acc[0][i] + bv0, l1 = acc[1][i] + bv1;
        float l2 = acc[2][i] + bv2, l3 = acc[3][i] + bv3;

        float m = fmaxf(fmaxf(l0, l1), fmaxf(l2, l3));
#pragma unroll
        for (int off = 8; off >= 1; off >>= 1)
            m = fmaxf(m, __shfl_xor(m, off, 64));

        float e0 = expf(l0 - m), e1 = expf(l1 - m);
        float e2 = expf(l2 - m), e3 = expf(l3 - m);
        float Z = e0 + e1 + e2 + e3;
#pragma unroll
        for (int off = 8; off >= 1; off >>= 1)
            Z += __shfl_xor(Z, off, 64);

        float lp0 = logf(e0 / Z + 1e-10f), lp1 = logf(e1 / Z + 1e-10f);
        float lp2 = logf(e2 / Z + 1e-10f), lp3 = logf(e3 / Z + 1e-10f);
        float slp = lp0 + lp1 + lp2 + lp3;
#pragma unroll
        for (int off = 8; off >= 1; off >>= 1)
            slp += __shfl_xor(slp, off, 64);

        // argmax, numpy first-index tie semantics (cols ascend with c, then lane)
        float bval = l0; int bcol = n16;
        if (l1 > bval) { bval = l1; bcol = 16 + n16; }
        if (l2 > bval) { bval = l2; bcol = 32 + n16; }
        if (l3 > bval) { bval = l3; bcol = 48 + n16; }
#pragma unroll
        for (int off = 8; off >= 1; off >>= 1) {
            float ov = __shfl_xor(bval, off, 64);
            int   oc = __shfl_xor(bcol, off, 64);
            if (ov > bval || (ov == bval && oc < bcol)) { bval = ov; bcol = oc; }
        }

        const int tag = tg[i];                       // uniform within 16-lane group
        const int csel = tag >> 4;
        float cand = (csel == 0) ? lp0 : (csel == 1) ? lp1 : (csel == 2) ? lp2 : lp3;
        float lptag = __shfl(cand, (lane & 48) | (tag & 15), 64);

        float sc = tag_to_score[tag];
        float s = powf(sc, (float)tt);
        float es = expf(s);
        float denom = 63.0f * e1c + es;
        float rowloss = -((e1c / denom) * (slp - lptag) + (es / denom) * lptag);

        if (n16 == 0) {
            loss_acc += rowloss;
            unsigned valid = (tag < NT - 3) ? 1u : 0u;
            valid_acc += valid;
            right_acc += (valid && bcol == tag) ? 1u : 0u;
        }
    }

#pragma unroll
    for (int off = 32; off >= 1; off >>= 1) {
        loss_acc += __shfl_xor(loss_acc, off, 64);
        right_acc += __shfl_xor((int)right_acc, off, 64);
        valid_acc += __shfl_xor((int)valid_acc, off, 64);
    }
    if (lane == 0) {
        atomicAdd(ws_loss, loss_acc);
        atomicAdd(ws_cnt + 0, right_acc);
        atomicAdd(ws_cnt + 1, valid_acc);
    }
}

__global__ void mlaner_final(const float* __restrict__ ws_loss,
                             const unsigned int* __restrict__ ws_cnt,
                             float* __restrict__ out)
{
    out[0] = ws_loss[0];
    out[1] = (float)ws_cnt[0] / (float)ws_cnt[1];
}

extern "C" void kernel_launch(void* const* d_in, const int* in_sizes, int n_in,
                              void* d_out, int out_size, void* d_ws, size_t ws_size,
                              hipStream_t stream)
{
    const float* x    = (const float*)d_in[0];   // [64,512,1536] fp32
    const float* W    = (const float*)d_in[1];   // [1536,64] fp32
    const float* b    = (const float*)d_in[2];   // [64] fp32
    const int*   tags = (const int*)d_in[3];     // [64,512]
    // d_in[4]: attention_mask — softmax-shift-invariant, unused.
    const float* t2s  = (const float*)d_in[5];   // [64] fp32
    const int*   tptr = (const int*)d_in[6];     // scalar t
    float* out = (float*)d_out;                  // [loss1, acc1]

    float* ws_loss = (float*)d_ws;
    unsigned int* ws_cnt = (unsigned int*)((char*)d_ws + 8);
    short8* bhi = (short8*)((char*)d_ws + WS_B_OFF);
    short8* blo = bhi + B_FRAGS;                 // needs ws_size >= ~394 KB

    hipMemsetAsync(d_ws, 0, 16, stream);
    mlaner_prepw<<<dim3(B_FRAGS / 256), dim3(256), 0, stream>>>(W, bhi, blo);
    mlaner_main<<<dim3(ROWS / 64), dim3(256), 0, stream>>>(
        x, bhi, blo, b, tags, t2s, tptr, ws_loss, ws_cnt);
    mlaner_final<<<dim3(1), dim3(1), 0, stream>>>(ws_loss, ws_cnt, out);
}

// Round 4
// 309.637 us; speedup vs baseline: 2.8666x; 1.2311x over previous
//
#include <hip/hip_runtime.h>
#include <hip/hip_bf16.h>

// B=64, L=512, H2=1536, T=64. logits = x@W + b -> softmax -> loss/acc.
// R4: bf16-split MFMA + global_load_lds DMA double-buffer.
//   - x ~ xh+xl, W ~ wh+wl (bf16 RNE + residual); x*W ~ xh*wh + xh*wl + xl*wh.
//   - 1 wave per block (16 rows), 2048 blocks -> 8 independent DMA pipelines
//     per CU; per-iter barrier drains interleave across blocks.
//   - DMA prefetch is un-sinkable by the compiler (no VGPR destination) --
//     the R2/R3 register-prefetch designs were both legally defeated.
//   - B loads (L2-hot) issued BEFORE the DMA each iter: FIFO vmcnt lets the
//     wait for B leave the younger DMA outstanding.

#define H2 1536
#define NT 64
#define ROWS (64 * 512)
#define KC 64                 // k per LDS buffer
#define NITER (H2 / KC)       // 24
#define KS2 (H2 / 32)         // 48 MFMA k-steps (B-fragment granularity)
#define NBLK (ROWS / 16)      // 2048 blocks, 1 wave each

typedef __attribute__((ext_vector_type(8))) short short8;
typedef __attribute__((ext_vector_type(4))) float f32x4;

#define B_FRAGS (KS2 * 4 * 64)   // 12288 fragments x 16B (hi), same (lo)

__device__ __forceinline__ short bf_hi(float f) {
    __hip_bfloat16 h = __float2bfloat16(f);          // RNE
    return __builtin_bit_cast(short, h);
}
__device__ __forceinline__ float bf_f(short s) {
    __hip_bfloat16 h = __builtin_bit_cast(__hip_bfloat16, s);
    return __bfloat162float(h);
}

// Pack W[k][n] ([1536][64] k-major) into MFMA B-fragment order.
// Fragment (s2, c, lane): k = s2*32 + (lane>>4)*8 + j, n = c*16 + (lane&15).
__global__ void mlaner_prepw(const float* __restrict__ W,
                             short8* __restrict__ bhi, short8* __restrict__ blo)
{
    const int tid = blockIdx.x * 256 + threadIdx.x;   // 0..12287
    const int L = tid & 63, c = (tid >> 6) & 3, s2 = tid >> 8;
    const int kbase = s2 * 32 + (L >> 4) * 8;
    const int n = c * 16 + (L & 15);
    short8 hi, lo;
#pragma unroll
    for (int j = 0; j < 8; ++j) {
        float w = W[(size_t)(kbase + j) * NT + n];
        short h = bf_hi(w);
        hi[j] = h;
        lo[j] = bf_hi(w - bf_f(h));
    }
    const int idx = (s2 * 4 + c) * 64 + L;
    bhi[idx] = hi;
    blo[idx] = lo;
}

__device__ __forceinline__ void cvt_split(float4 a0, float4 a1,
                                          short8& hi, short8& lo)
{
    float v[8] = {a0.x, a0.y, a0.z, a0.w, a1.x, a1.y, a1.z, a1.w};
#pragma unroll
    for (int j = 0; j < 8; ++j) {
        short h = bf_hi(v[j]);
        hi[j] = h;
        lo[j] = bf_hi(v[j] - bf_f(h));
    }
}

__global__ __launch_bounds__(64, 2) void mlaner_main(
    const float* __restrict__ x,
    const short8* __restrict__ Bhi, const short8* __restrict__ Blo,
    const float* __restrict__ bias, const int* __restrict__ tags,
    const float* __restrict__ tag_to_score, const int* __restrict__ tptr,
    float* __restrict__ ploss, unsigned* __restrict__ pright,
    unsigned* __restrict__ pvalid)
{
    __shared__ float lds[2][KC * 16];     // 2 x 4KB

    const int lane = threadIdx.x;
    const int blk = blockIdx.x;
    const int row0 = blk * 16;
    const int q = lane >> 4, n16 = lane & 15;

    // DMA one 4KB chunk (16 rows x 64 k) into buffer b; 4 x 1KB issues.
    // LDS dest is wave-uniform base + lane*16 (HW rule). Global side applies
    // the bank swizzle: 16B slot j of row r holds global k-slot j^(r&7).
    auto dma = [&](int b, int s) {
#pragma unroll
        for (int i = 0; i < 4; ++i) {
            const int idx = i * 64 + lane;          // 0..255 slot index
            const int r = idx >> 4, j = idx & 15;
            const int jg = j ^ (r & 7);
            const float* gp = x + (size_t)(row0 + r) * H2 + s * KC + jg * 4;
            __builtin_amdgcn_global_load_lds(
                (const __attribute__((address_space(1))) void*)gp,
                (__attribute__((address_space(3))) void*)&lds[b][i * 256],
                16, 0, 0);
        }
    };

    f32x4 acc[4];
#pragma unroll
    for (int c = 0; c < 4; ++c) acc[c] = (f32x4){0.f, 0.f, 0.f, 0.f};

    dma(0, 0);
    __syncthreads();                       // drain DMA(0)

#pragma unroll 1
    for (int s = 0; s < NITER; ++s) {
        // B fragments for both 32-k halves of this chunk (used this iter ->
        // not sinkable). Issued before the DMA so the B-wait is vmcnt(4).
        short8 bh[2][4], bl[2][4];
#pragma unroll
        for (int h = 0; h < 2; ++h)
#pragma unroll
            for (int c = 0; c < 4; ++c) {
                const int f = ((s * 2 + h) * 4 + c) * 64 + lane;
                bh[h][c] = Bhi[f];
                bl[h][c] = Blo[f];
            }

        if (s + 1 < NITER) dma((s + 1) & 1, s + 1);

        const float* bufp = &lds[s & 1][0];
#pragma unroll
        for (int h = 0; h < 2; ++h) {
            // A-fragment: lane(q,n16) = row n16, k = h*32 + q*8 + [0..8)
            const int sg0 = (h * 8 + 2 * q)     ^ (n16 & 7);
            const int sg1 = (h * 8 + 2 * q + 1) ^ (n16 & 7);
            float4 a0 = *(const float4*)&bufp[n16 * 64 + sg0 * 4];
            float4 a1 = *(const float4*)&bufp[n16 * 64 + sg1 * 4];
            short8 ah, al;
            cvt_split(a0, a1, ah, al);
#pragma unroll
            for (int c = 0; c < 4; ++c) {
                acc[c] = __builtin_amdgcn_mfma_f32_16x16x32_bf16(ah, bh[h][c], acc[c], 0, 0, 0);
                acc[c] = __builtin_amdgcn_mfma_f32_16x16x32_bf16(ah, bl[h][c], acc[c], 0, 0, 0);
                acc[c] = __builtin_amdgcn_mfma_f32_16x16x32_bf16(al, bh[h][c], acc[c], 0, 0, 0);
            }
        }
        __syncthreads();   // drain DMA(s+1); protect buffer reuse
    }

    // ---- epilogue ----
    // C/D layout: col = c*16 + n16, row(local) = q*4 + i  [m89-verified]
    // attention_mask adds a row constant -> softmax/argmax invariant; skipped.
    const float bv0 = bias[n16], bv1 = bias[16 + n16];
    const float bv2 = bias[32 + n16], bv3 = bias[48 + n16];
    int tg[4];
#pragma unroll
    for (int i = 0; i < 4; ++i) tg[i] = tags[row0 + q * 4 + i];
    const int tt = tptr[0];
    const float e1c = expf(1.0f);
    float loss_acc = 0.0f;
    unsigned right_acc = 0, valid_acc = 0;

#pragma unroll 1
    for (int i = 0; i < 4; ++i) {
        float l0 = acc[0][i] + bv0, l1 = acc[1][i] + bv1;
        float l2 = acc[2][i] + bv2, l3 = acc[3][i] + bv3;

        float m = fmaxf(fmaxf(l0, l1), fmaxf(l2, l3));
#pragma unroll
        for (int off = 8; off >= 1; off >>= 1)
            m = fmaxf(m, __shfl_xor(m, off, 64));

        float e0 = expf(l0 - m), e1 = expf(l1 - m);
        float e2 = expf(l2 - m), e3 = expf(l3 - m);
        float Z = e0 + e1 + e2 + e3;
#pragma unroll
        for (int off = 8; off >= 1; off >>= 1)
            Z += __shfl_xor(Z, off, 64);

        float lp0 = logf(e0 / Z + 1e-10f), lp1 = logf(e1 / Z + 1e-10f);
        float lp2 = logf(e2 / Z + 1e-10f), lp3 = logf(e3 / Z + 1e-10f);
        float slp = lp0 + lp1 + lp2 + lp3;
#pragma unroll
        for (int off = 8; off >= 1; off >>= 1)
            slp += __shfl_xor(slp, off, 64);

        // argmax, numpy first-index tie semantics
        float bval = l0; int bcol = n16;
        if (l1 > bval) { bval = l1; bcol = 16 + n16; }
        if (l2 > bval) { bval = l2; bcol = 32 + n16; }
        if (l3 > bval) { bval = l3; bcol = 48 + n16; }
#pragma unroll
        for (int off = 8; off >= 1; off >>= 1) {
            float ov = __shfl_xor(bval, off, 64);
            int   oc = __shfl_xor(bcol, off, 64);
            if (ov > bval || (ov == bval && oc < bcol)) { bval = ov; bcol = oc; }
        }

        const int tag = tg[i];                 // uniform within 16-lane group
        const int csel = tag >> 4;
        float cand = (csel == 0) ? lp0 : (csel == 1) ? lp1 : (csel == 2) ? lp2 : lp3;
        float lptag = __shfl(cand, (lane & 48) | (tag & 15), 64);

        float sc = tag_to_score[tag];
        float sp = powf(sc, (float)tt);
        float es = expf(sp);
        float denom = 63.0f * e1c + es;
        float rowloss = -((e1c / denom) * (slp - lptag) + (es / denom) * lptag);

        if (n16 == 0) {
            loss_acc += rowloss;
            unsigned valid = (tag < NT - 3) ? 1u : 0u;
            valid_acc += valid;
            right_acc += (valid && bcol == tag) ? 1u : 0u;
        }
    }

#pragma unroll
    for (int off = 32; off >= 1; off >>= 1) {
        loss_acc += __shfl_xor(loss_acc, off, 64);
        right_acc += __shfl_xor((int)right_acc, off, 64);
        valid_acc += __shfl_xor((int)valid_acc, off, 64);
    }
    if (lane == 0) {
        ploss[blk] = loss_acc;
        pright[blk] = right_acc;
        pvalid[blk] = valid_acc;
    }
}

__global__ void mlaner_final(const float* __restrict__ pl,
                             const unsigned* __restrict__ pr,
                             const unsigned* __restrict__ pv,
                             float* __restrict__ out)
{
    __shared__ float sl[4];
    __shared__ unsigned sr[4], sv[4];
    const int tid = threadIdx.x, lane = tid & 63, wv = tid >> 6;
    float l = 0.0f; unsigned r = 0, v = 0;
    for (int i = tid; i < NBLK; i += 256) { l += pl[i]; r += pr[i]; v += pv[i]; }
#pragma unroll
    for (int off = 32; off >= 1; off >>= 1) {
        l += __shfl_xor(l, off, 64);
        r += __shfl_xor((int)r, off, 64);
        v += __shfl_xor((int)v, off, 64);
    }
    if (lane == 0) { sl[wv] = l; sr[wv] = r; sv[wv] = v; }
    __syncthreads();
    if (tid == 0) {
        float L = sl[0] + sl[1] + sl[2] + sl[3];
        unsigned R = sr[0] + sr[1] + sr[2] + sr[3];
        unsigned V = sv[0] + sv[1] + sv[2] + sv[3];
        out[0] = L;
        out[1] = (float)R / (float)V;
    }
}

extern "C" void kernel_launch(void* const* d_in, const int* in_sizes, int n_in,
                              void* d_out, int out_size, void* d_ws, size_t ws_size,
                              hipStream_t stream)
{
    const float* x    = (const float*)d_in[0];   // [64,512,1536] fp32
    const float* W    = (const float*)d_in[1];   // [1536,64] fp32
    const float* b    = (const float*)d_in[2];   // [64] fp32
    const int*   tags = (const int*)d_in[3];     // [64,512]
    // d_in[4]: attention_mask — softmax-shift-invariant, unused.
    const float* t2s  = (const float*)d_in[5];   // [64] fp32
    const int*   tptr = (const int*)d_in[6];     // scalar t
    float* out = (float*)d_out;                  // [loss1, acc1]

    // ws layout: Bhi | Blo | ploss[2048] | pright[2048] | pvalid[2048]
    short8* bhi = (short8*)d_ws;
    short8* blo = bhi + B_FRAGS;
    float* ploss = (float*)((char*)d_ws + (size_t)2 * B_FRAGS * 16);
    unsigned* pright = (unsigned*)(ploss + NBLK);
    unsigned* pvalid = pright + NBLK;
    // needs ws_size >= 393216 + 24576 bytes

    mlaner_prepw<<<dim3(B_FRAGS / 256), dim3(256), 0, stream>>>(W, bhi, blo);
    mlaner_main<<<dim3(NBLK), dim3(64), 0, stream>>>(
        x, bhi, blo, b, tags, t2s, tptr, ploss, pright, pvalid);
    mlaner_final<<<dim3(1), dim3(256), 0, stream>>>(ploss, pright, pvalid, out);
}